// Round 7
// baseline (645.977 us; speedup 1.0000x reference)
//
#include <hip/hip_runtime.h>
#include <hip/hip_bf16.h>
#include <math.h>

typedef __hip_bfloat16 bf16;
typedef unsigned short ushort;
static __device__ __forceinline__ float b2f(bf16 x){ return __bfloat162float(x); }

// flag-aware load: isbf!=0 -> buffer is bf16, else fp32
static __device__ __forceinline__ float ldf(const void* p, int i, int isbf){
    return isbf ? b2f(((const bf16*)p)[i]) : ((const float*)p)[i];
}

#define NN    4096
#define FEAT0 500
#define DIN   512
#define NH    256
#define KL1   3072
#define KL2   2304
#define KL3   1728
#define EDGE_CAP 1048576u

typedef __attribute__((ext_vector_type(8)))  short v8s;   // 8 bf16 in 4 VGPRs
typedef __attribute__((ext_vector_type(16))) float v16f;  // 32x32 MFMA acc

// ---------------- per-tensor dtype autodetect ----------------
struct DtIn { const void* p[19]; int n[19]; };
__global__ void k_dtype_all(DtIn a, unsigned* flags){
    int t = threadIdx.x;
    if (t < 19){
        const unsigned short* h = (const unsigned short*)a.p[t];
        int n = a.n[t]; if (n > 256) n = 256;
        int isbf = 1;
        for (int i = 0; i < n; i++){
            unsigned e = ((unsigned)h[i] >> 7) & 0xFFu;
            if (e >= 135u) isbf = 0;
        }
        flags[t] = (unsigned)isbf;
    }
}

// ---------------- init ----------------
__global__ void k_init(float* degA, float* out_acc, unsigned* ecnt, unsigned* maxd2){
    int i = blockIdx.x*256 + threadIdx.x;
    if (i < NN)  degA[i] = 1.0f;          // self-loop
    if (i < 512) out_acc[i] = 0.f;
    if (i == 0){ ecnt[0]=0u; ecnt[1]=0u; ecnt[2]=0u; maxd2[0]=0u; }
}

// ---------------- pos MLP + concat; write fp32 X, bf16 Xb, sq(from bf16) ---
__global__ __launch_bounds__(512) void k_posconcat(const void* __restrict__ feature,
        const void* __restrict__ img, const void* __restrict__ Wpos, const void* __restrict__ bpos,
        const unsigned* __restrict__ dflag, float* __restrict__ X, ushort* __restrict__ Xb,
        float* __restrict__ sq){
    int f_feat = (int)dflag[0], f_img = (int)dflag[1], f_wp = (int)dflag[2], f_bp = (int)dflag[3];
    int row = blockIdx.x, t = threadIdx.x;
    float v;
    if (t < FEAT0) v = ldf(feature, row*FEAT0 + t, f_feat);
    else {
        int c = t - FEAT0;
        float acc = ldf(bpos, c, f_bp);
        #pragma unroll
        for (int d = 0; d < 6; d++) acc += ldf(img, row*6+d, f_img) * ldf(Wpos, d*12+c, f_wp);
        v = fmaxf(acc, 0.f);
    }
    X[row*DIN + t] = v;
    bf16 vb = __float2bfloat16(v);
    Xb[row*DIN + t] = __bfloat16_as_ushort(vb);
    float vr = b2f(vb);                 // sq from rounded values: d2 is exact
    __shared__ float red[512];          // squared distance of the bf16 vectors
    red[t] = vr*vr;
    __syncthreads();
    for (int s = 256; s > 0; s >>= 1){ if (t < s) red[t] += red[t+s]; __syncthreads(); }
    if (t == 0) sq[row] = red[0];
}

// ---------------- Gram via MFMA, 128x128 tile, LDS-staged, XOR-swizzled ----
// 4 waves, each computes a 64x64 quadrant as 2x2 MFMA 32x32 blocks.
// __launch_bounds__(256,2): 2 waves/EU -> 256-VGPR budget. Round 6 lesson:
// default heuristic capped at 84 VGPRs and spilled the 64-reg accumulator
// set to scratch (45 MB WRITE_SIZE, MfmaUtil 3.9%).
template<int PASS>
__global__ __launch_bounds__(256, 2) void k_gram(const ushort* __restrict__ Xb,
        const float* __restrict__ sq, unsigned* __restrict__ maxd2,
        unsigned* __restrict__ ecnt, unsigned* __restrict__ edges, float* __restrict__ deg){
    int rb = blockIdx.x, cb = blockIdx.y;
    if (cb > rb) return;                  // lower triangle only (uniform exit)
    __shared__ __align__(16) ushort As[128*64];
    __shared__ __align__(16) ushort Bs[128*64];
    int tid = threadIdx.x;
    int lane = tid & 63, wv = tid >> 6;
    int wwr = wv >> 1, wwc = wv & 1;      // wave quadrant of the 128x128 tile
    int l31 = lane & 31, hi = lane >> 5;
    int r7 = l31 & 7;

    // staging map: 4 rounds x 256 threads x 16B cover one 128x64-bf16 panel chunk
    int srow[4], sgr[4];
    #pragma unroll
    for (int q = 0; q < 4; q++){
        int l = q*256 + tid;
        srow[q] = l >> 3;                 // panel row 0..127
        sgr[q]  = l & 7;                  // 16B granule within 128B row-chunk
    }
    const size_t baseA = (size_t)rb*128*DIN;
    const size_t baseB = (size_t)cb*128*DIN;

    float4 pva[4], pvb[4];
    #pragma unroll
    for (int q = 0; q < 4; q++){
        size_t o = (size_t)srow[q]*DIN + sgr[q]*8;
        pva[q] = *(const float4*)(Xb + baseA + o);
        pvb[q] = *(const float4*)(Xb + baseB + o);
    }

    v16f acc00 = {}, acc01 = {}, acc10 = {}, acc11 = {};
    int ra0 = (wwr*64 + l31)*64;          // LDS ushort index of A frag row
    int rb0 = (wwc*64 + l31)*64;

    for (int c = 0; c < 8; c++){
        __syncthreads();                  // prior chunk's reads complete
        #pragma unroll
        for (int q = 0; q < 4; q++){
            int di = srow[q]*64 + ((sgr[q]^(srow[q]&7))<<3);
            *(float4*)&As[di] = pva[q];
            *(float4*)&Bs[di] = pvb[q];
        }
        __syncthreads();
        if (c < 7){
            int k0 = (c+1)*64;
            #pragma unroll
            for (int q = 0; q < 4; q++){
                size_t o = (size_t)srow[q]*DIN + k0 + sgr[q]*8;
                pva[q] = *(const float4*)(Xb + baseA + o);
                pvb[q] = *(const float4*)(Xb + baseB + o);
            }
        }
        #pragma unroll
        for (int ks = 0; ks < 4; ks++){
            int g = (((ks*2 + hi) ^ r7) << 3);
            v8s a0 = *(const v8s*)&As[ra0 + g];
            v8s a1 = *(const v8s*)&As[ra0 + 2048 + g];
            v8s b0 = *(const v8s*)&Bs[rb0 + g];
            v8s b1 = *(const v8s*)&Bs[rb0 + 2048 + g];
            acc00 = __builtin_amdgcn_mfma_f32_32x32x16_bf16(a0, b0, acc00, 0, 0, 0);
            acc01 = __builtin_amdgcn_mfma_f32_32x32x16_bf16(a0, b1, acc01, 0, 0, 0);
            acc10 = __builtin_amdgcn_mfma_f32_32x32x16_bf16(a1, b0, acc10, 0, 0, 0);
            acc11 = __builtin_amdgcn_mfma_f32_32x32x16_bf16(a1, b1, acc11, 0, 0, 0);
        }
    }

    float tthr = 0.f;
    if (PASS == 2) tthr = 0.5f * __uint_as_float(maxd2[0]);
    float m = 0.f;
    #pragma unroll
    for (int qr = 0; qr < 2; qr++){
        #pragma unroll
        for (int qc = 0; qc < 2; qc++){
            v16f A = qr ? (qc ? acc11 : acc10) : (qc ? acc01 : acc00);
            int rbase = rb*128 + wwr*64 + qr*32 + 4*hi;
            int col   = cb*128 + wwc*64 + qc*32 + l31;
            float sqc = sq[col];
            #pragma unroll
            for (int i = 0; i < 16; i++){
                int r = rbase + (i&3) + 8*(i>>2);
                float d2 = sq[r] + sqc - 2.f*A[i];
                if (PASS == 1){
                    if (r != col) m = fmaxf(m, d2);
                } else {
                    if (r > col && d2 < tthr){
                        unsigned idx = atomicAdd(ecnt, 1u);
                        if (idx < EDGE_CAP){
                            edges[idx] = ((unsigned)r << 16) | (unsigned)col;  // dst<<16|src
                            atomicAdd(&deg[r], 1.0f);
                        }
                    }
                }
            }
        }
    }
    if (PASS == 1){
        #pragma unroll
        for (int off = 32; off >= 1; off >>= 1) m = fmaxf(m, __shfl_down(m, off));
        if (lane == 0) atomicMax(maxd2, __float_as_uint(fmaxf(m, 0.f)));
    }
}

// ---------------- X @ W (fp32 x flag-dtype -> fp32), 64x64 tiles ----------------
__global__ __launch_bounds__(256) void k_xw(const float* __restrict__ X, const void* __restrict__ W,
        const unsigned* __restrict__ wflag, float* __restrict__ Y, int M, int K){
    int isbf = (int)wflag[0];
    int rb = blockIdx.x, cb = blockIdx.y;      // grid (M/64, 4)
    __shared__ float As[16][68];
    __shared__ float Bs[16][68];
    int tid = threadIdx.x;
    int tx = tid & 15, ty = tid >> 4;
    int lr = tid >> 2, lk = (tid & 3) << 2;    // A-tile load mapping
    int bn = tid & 63, bk4 = (tid >> 6) << 2;  // B-tile load mapping
    const float* Ap = X + (size_t)(rb*64 + lr)*K + lk;
    float acc[4][4] = {};
    for (int k0 = 0; k0 < K; k0 += 16){
        float4 fa = *(const float4*)(Ap + k0);
        int wb = cb*64 + bn;
        float w0 = ldf(W, (k0+bk4+0)*NH + wb, isbf);
        float w1 = ldf(W, (k0+bk4+1)*NH + wb, isbf);
        float w2 = ldf(W, (k0+bk4+2)*NH + wb, isbf);
        float w3 = ldf(W, (k0+bk4+3)*NH + wb, isbf);
        __syncthreads();
        As[lk+0][lr]=fa.x; As[lk+1][lr]=fa.y; As[lk+2][lr]=fa.z; As[lk+3][lr]=fa.w;
        Bs[bk4+0][bn]=w0; Bs[bk4+1][bn]=w1; Bs[bk4+2][bn]=w2; Bs[bk4+3][bn]=w3;
        __syncthreads();
        #pragma unroll
        for (int kk = 0; kk < 16; kk++){
            const float4 av = *(const float4*)(&As[kk][ty<<2]);
            const float4 bv = *(const float4*)(&Bs[kk][tx<<2]);
            const float ar[4] = {av.x,av.y,av.z,av.w};
            const float br[4] = {bv.x,bv.y,bv.z,bv.w};
            #pragma unroll
            for (int i = 0; i < 4; i++)
                #pragma unroll
                for (int j = 0; j < 4; j++)
                    acc[i][j] = fmaf(ar[i], br[j], acc[i][j]);
        }
    }
    int r0 = rb*64 + (ty<<2), c0 = cb*64 + (tx<<2);
    #pragma unroll
    for (int i = 0; i < 4; i++)
        #pragma unroll
        for (int j = 0; j < 4; j++)
            Y[(size_t)(r0+i)*NH + (c0+j)] = acc[i][j];
}

// xw' = dis*xw (in place) ; agg = xw' (self term of A+I)
__global__ void k_scaleself(float* __restrict__ xw, float* __restrict__ agg,
        const float* __restrict__ deg, int N){
    int idx = blockIdx.x*256 + threadIdx.x;
    if (idx >= N*NH) return;
    int row = idx >> 8;
    float dis = 1.0f / sqrtf(deg[row]);
    float v = xw[idx] * dis;
    xw[idx] = v; agg[idx] = v;
}

// agg[dst] += xw'[src] for each edge
__global__ __launch_bounds__(256) void k_edgeagg(const unsigned* __restrict__ edges,
        const unsigned* __restrict__ ecnt, int slot,
        const float* __restrict__ xwp, float* __restrict__ agg){
    unsigned E = ecnt[slot]; if (E > EDGE_CAP) E = EDGE_CAP;
    int t = threadIdx.x;
    for (unsigned e = blockIdx.x; e < E; e += gridDim.x){
        unsigned ed = edges[e];
        int dst = ed >> 16, src = ed & 0xFFFFu;
        atomicAdd(&agg[dst*NH + t], xwp[src*NH + t]);
    }
}

// x = relu(dis*agg + b)
__global__ void k_gcnfin(const float* __restrict__ agg, const float* __restrict__ deg,
        const void* __restrict__ b, const unsigned* __restrict__ bflag,
        float* __restrict__ xout, int N){
    int isbf = (int)bflag[0];
    int idx = blockIdx.x*256 + threadIdx.x;
    if (idx >= N*NH) return;
    int row = idx >> 8, c = idx & 255;
    float dis = 1.0f / sqrtf(deg[row]);
    xout[idx] = fmaxf(fmaf(dis, agg[idx], ldf(b, c, isbf)), 0.f);
}

// per-row: s1 = x.Wn ; z = x.Wr + bs
__global__ __launch_bounds__(256) void k_scorer(const float* __restrict__ X,
        const void* __restrict__ Wn, const void* __restrict__ Wr, const void* __restrict__ bs,
        const unsigned* __restrict__ fWn, const unsigned* __restrict__ fWr,
        const unsigned* __restrict__ fbs, float* __restrict__ s1, float* __restrict__ z){
    int isWn = (int)fWn[0], isWr = (int)fWr[0], isbs = (int)fbs[0];
    int row = blockIdx.x, t = threadIdx.x;
    float xv = X[row*NH + t];
    float a = xv * ldf(Wn, t, isWn);
    float b = xv * ldf(Wr, t, isWr);
    for (int off = 32; off >= 1; off >>= 1){ a += __shfl_down(a, off); b += __shfl_down(b, off); }
    __shared__ float ra[4], rb[4];
    int w = t >> 6;
    if ((t & 63) == 0){ ra[w] = a; rb[w] = b; }
    __syncthreads();
    if (t == 0){
        s1[row] = ra[0]+ra[1]+ra[2]+ra[3];
        z[row]  = rb[0]+rb[1]+rb[2]+rb[3] + ldf(bs, 0, isbs);
    }
}

// z[dst] += s1[src] per edge
__global__ void k_scoredge(const unsigned* __restrict__ edges, const unsigned* __restrict__ ecnt,
        int slot, const float* __restrict__ s1, float* __restrict__ z){
    unsigned E = ecnt[slot]; if (E > EDGE_CAP) E = EDGE_CAP;
    int gid = blockIdx.x*blockDim.x + threadIdx.x;
    int stride = gridDim.x*blockDim.x;
    for (unsigned e = gid; e < E; e += stride)
        atomicAdd(&z[edges[e] >> 16], s1[edges[e] & 0xFFFFu]);
}

// single-block bitonic sort of (tanh(z), idx), descending score, ties -> lower idx
__global__ __launch_bounds__(1024) void k_sort(const float* __restrict__ z, int N,
        int* __restrict__ perm, float* __restrict__ svals){
    __shared__ float sv[4096];
    __shared__ int   si[4096];
    int t = threadIdx.x;
    for (int i = t; i < 4096; i += 1024){
        sv[i] = (i < N) ? tanhf(z[i]) : -INFINITY;
        si[i] = i;
    }
    __syncthreads();
    for (int k = 2; k <= 4096; k <<= 1){
        for (int j = k >> 1; j > 0; j >>= 1){
            for (int i = t; i < 4096; i += 1024){
                int ixj = i ^ j;
                if (ixj > i){
                    bool dirAsc = ((i & k) == 0);
                    float v1 = sv[i], v2 = sv[ixj];
                    int  i1 = si[i], i2 = si[ixj];
                    bool after = (v1 < v2) || (v1 == v2 && i1 > i2);
                    if (after == dirAsc){ sv[i]=v2; sv[ixj]=v1; si[i]=i2; si[ixj]=i1; }
                }
            }
            __syncthreads();
        }
    }
    for (int i = t; i < 4096; i += 1024){ perm[i] = si[i]; svals[i] = sv[i]; }
}

__global__ void k_rankdeg(int* __restrict__ rank, int Ncur, float* __restrict__ degN, int Nnext){
    int i = blockIdx.x*256 + threadIdx.x;
    if (i < Ncur)  rank[i] = -1;
    if (i < Nnext) degN[i] = 1.0f;
}

// pooled x = x[perm[r]] * vals[r] ; also scatter rank
__global__ void k_poolx(const float* __restrict__ X, const int* __restrict__ perm,
        const float* __restrict__ svals, float* __restrict__ Y, int* __restrict__ rank,
        int k, int doRank){
    int idx = blockIdx.x*256 + threadIdx.x;
    int r = idx >> 8, c = idx & 255;
    if (r >= k) return;
    int p = perm[r];
    Y[idx] = X[p*NH + c] * svals[r];
    if (doRank && c == 0) rank[p] = r;
}

// filter surviving edges, renumber, accumulate next-layer degree
__global__ void k_efilter(const unsigned* __restrict__ ein, const unsigned* __restrict__ ecnt, int slotIn,
        unsigned* __restrict__ eout, unsigned* __restrict__ cntOut,
        const int* __restrict__ rank, float* __restrict__ degN){
    unsigned E = ecnt[slotIn]; if (E > EDGE_CAP) E = EDGE_CAP;
    int gid = blockIdx.x*blockDim.x + threadIdx.x;
    int stride = gridDim.x*blockDim.x;
    for (unsigned e = gid; e < E; e += stride){
        unsigned ed = ein[e];
        int nd = rank[ed >> 16], ns = rank[ed & 0xFFFFu];
        if (nd >= 0 && ns >= 0){
            unsigned idx = atomicAdd(cntOut, 1u);
            if (idx < EDGE_CAP){
                eout[idx] = ((unsigned)nd << 16) | (unsigned)ns;
                atomicAdd(&degN[nd], 1.0f);
            }
        }
    }
}

// readout: partial col-max/col-sum over 64 row-stripes, then combine into out_acc
__global__ __launch_bounds__(256) void k_rpart(const float* __restrict__ X, int k,
        float* __restrict__ pmax, float* __restrict__ psum){
    int b = blockIdx.x, t = threadIdx.x;
    float m = -INFINITY, s = 0.f;
    for (int r = b; r < k; r += 64){
        float v = X[r*NH + t];
        m = fmaxf(m, v); s += v;
    }
    pmax[b*NH + t] = m; psum[b*NH + t] = s;
}
__global__ __launch_bounds__(256) void k_rfin(const float* __restrict__ pmax,
        const float* __restrict__ psum, float* __restrict__ out_acc, float invk){
    int t = threadIdx.x;
    float m = -INFINITY, s = 0.f;
    for (int b = 0; b < 64; b++){ m = fmaxf(m, pmax[b*NH+t]); s += psum[b*NH+t]; }
    out_acc[t]      += m;
    out_acc[NH + t] += s * invk;
}

__global__ void k_writeout(const float* __restrict__ out_acc, float* __restrict__ out){
    int t = blockIdx.x*256 + threadIdx.x;
    if (t < 512) out[t] = out_acc[t];
}

// =======================================================================
extern "C" void kernel_launch(void* const* d_in, const int* in_sizes, int n_in,
                              void* d_out, int out_size, void* d_ws, size_t ws_size,
                              hipStream_t stream)
{
    const void* feature = d_in[0];
    const void* img     = d_in[1];
    const void* Wpos    = d_in[2];
    const void* bpos    = d_in[3];
    const void* W1 = d_in[4];  const void* b1 = d_in[5];
    const void* W2 = d_in[6];  const void* b2 = d_in[7];
    const void* W3 = d_in[8];  const void* b3 = d_in[9];
    const void* Wr1 = d_in[10]; const void* Wn1 = d_in[11]; const void* bs1 = d_in[12];
    const void* Wr2 = d_in[13]; const void* Wn2 = d_in[14]; const void* bs2 = d_in[15];
    const void* Wr3 = d_in[16]; const void* Wn3 = d_in[17]; const void* bs3 = d_in[18];

    char* w = (char*)d_ws;
    auto alloc = [&](size_t bytes)->char*{ char* p = w; w += (bytes + 255) & ~(size_t)255; return p; };
    float*    X      = (float*)   alloc((size_t)NN*DIN*4);  // 8 MB: feat, then pooled x
    ushort*   Xb     = (ushort*)  alloc((size_t)NN*DIN*2);  // 4 MB: bf16 X for MFMA gram
    float*    Xn     = (float*)   alloc((size_t)NN*NH*4);   // 4 MB
    float*    XW     = (float*)   alloc((size_t)NN*NH*4);   // 4 MB
    float*    AGG    = (float*)   alloc((size_t)NN*NH*4);   // 4 MB
    unsigned* E0     = (unsigned*)alloc((size_t)EDGE_CAP*4);// 4 MB
    unsigned* E1     = (unsigned*)alloc((size_t)EDGE_CAP*4);// 4 MB
    float*    sq     = (float*)   alloc(NN*4);
    float*    degA   = (float*)   alloc(NN*4);
    float*    degB   = (float*)   alloc(NN*4);
    float*    s1     = (float*)   alloc(NN*4);
    float*    z      = (float*)   alloc(NN*4);
    int*      perm   = (int*)     alloc(NN*4);
    float*    svals  = (float*)   alloc(NN*4);
    int*      rank   = (int*)     alloc(NN*4);
    unsigned* ecnt   = (unsigned*)alloc(256);
    unsigned* maxd2  = (unsigned*)alloc(256);
    unsigned* dflag  = (unsigned*)alloc(256);
    float*    outacc = (float*)   alloc(512*4);
    float*    pmax   = (float*)   alloc(64*NH*4);
    float*    psum   = (float*)   alloc(64*NH*4);
    (void)ws_size;

    DtIn da;
    for (int i = 0; i < 19; i++){ da.p[i] = d_in[i]; da.n[i] = in_sizes[i]; }
    k_dtype_all<<<1, 64, 0, stream>>>(da, dflag);
    k_init<<<16, 256, 0, stream>>>(degA, outacc, ecnt, maxd2);
    k_posconcat<<<NN, 512, 0, stream>>>(feature, img, Wpos, bpos, dflag, X, Xb, sq);
    dim3 gg(32, 32);
    k_gram<1><<<gg, 256, 0, stream>>>(Xb, sq, maxd2, ecnt, E0, degA);
    k_gram<2><<<gg, 256, 0, stream>>>(Xb, sq, maxd2, ecnt, E0, degA);

    // ---------------- layer 1 (N=4096 -> k=3072) ----------------
    k_xw<<<dim3(64,4), 256, 0, stream>>>(X, W1, dflag+4, XW, NN, DIN);
    k_scaleself<<<NN, 256, 0, stream>>>(XW, AGG, degA, NN);
    k_edgeagg<<<512, 256, 0, stream>>>(E0, ecnt, 0, XW, AGG);
    k_gcnfin<<<NN, 256, 0, stream>>>(AGG, degA, b1, dflag+5, Xn, NN);
    k_scorer<<<NN, 256, 0, stream>>>(Xn, Wn1, Wr1, bs1, dflag+11, dflag+10, dflag+12, s1, z);
    k_scoredge<<<256, 256, 0, stream>>>(E0, ecnt, 0, s1, z);
    k_sort<<<1, 1024, 0, stream>>>(z, NN, perm, svals);
    k_rankdeg<<<16, 256, 0, stream>>>(rank, NN, degB, KL1);
    k_poolx<<<KL1, 256, 0, stream>>>(Xn, perm, svals, X, rank, KL1, 1);
    k_rpart<<<64, 256, 0, stream>>>(X, KL1, pmax, psum);
    k_rfin<<<1, 256, 0, stream>>>(pmax, psum, outacc, 1.0f/KL1);
    k_efilter<<<256, 256, 0, stream>>>(E0, ecnt, 0, E1, ecnt+1, rank, degB);

    // ---------------- layer 2 (N=3072 -> k=2304) ----------------
    k_xw<<<dim3(48,4), 256, 0, stream>>>(X, W2, dflag+6, XW, KL1, NH);
    k_scaleself<<<KL1, 256, 0, stream>>>(XW, AGG, degB, KL1);
    k_edgeagg<<<512, 256, 0, stream>>>(E1, ecnt, 1, XW, AGG);
    k_gcnfin<<<KL1, 256, 0, stream>>>(AGG, degB, b2, dflag+7, Xn, KL1);
    k_scorer<<<KL1, 256, 0, stream>>>(Xn, Wn2, Wr2, bs2, dflag+14, dflag+13, dflag+15, s1, z);
    k_scoredge<<<256, 256, 0, stream>>>(E1, ecnt, 1, s1, z);
    k_sort<<<1, 1024, 0, stream>>>(z, KL1, perm, svals);
    k_rankdeg<<<16, 256, 0, stream>>>(rank, KL1, degA, KL2);
    k_poolx<<<KL2, 256, 0, stream>>>(Xn, perm, svals, X, rank, KL2, 1);
    k_rpart<<<64, 256, 0, stream>>>(X, KL2, pmax, psum);
    k_rfin<<<1, 256, 0, stream>>>(pmax, psum, outacc, 1.0f/KL2);
    k_efilter<<<256, 256, 0, stream>>>(E1, ecnt, 1, E0, ecnt+2, rank, degA);

    // ---------------- layer 3 (N=2304 -> k=1728) ----------------
    k_xw<<<dim3(36,4), 256, 0, stream>>>(X, W3, dflag+8, XW, KL2, NH);
    k_scaleself<<<KL2, 256, 0, stream>>>(XW, AGG, degA, KL2);
    k_edgeagg<<<512, 256, 0, stream>>>(E0, ecnt, 2, XW, AGG);
    k_gcnfin<<<KL2, 256, 0, stream>>>(AGG, degA, b3, dflag+9, Xn, KL2);
    k_scorer<<<KL2, 256, 0, stream>>>(Xn, Wn3, Wr3, bs3, dflag+17, dflag+16, dflag+18, s1, z);
    k_scoredge<<<256, 256, 0, stream>>>(E0, ecnt, 2, s1, z);
    k_sort<<<1, 1024, 0, stream>>>(z, KL2, perm, svals);
    k_poolx<<<KL3, 256, 0, stream>>>(Xn, perm, svals, X, rank, KL3, 0);
    k_rpart<<<64, 256, 0, stream>>>(X, KL3, pmax, psum);
    k_rfin<<<1, 256, 0, stream>>>(pmax, psum, outacc, 1.0f/KL3);

    k_writeout<<<2, 256, 0, stream>>>(outacc, (float*)d_out);
}

// Round 8
// 613.112 us; speedup vs baseline: 1.0536x; 1.0536x over previous
//
#include <hip/hip_runtime.h>
#include <hip/hip_bf16.h>
#include <math.h>

typedef __hip_bfloat16 bf16;
typedef unsigned short ushort;
static __device__ __forceinline__ float b2f(bf16 x){ return __bfloat162float(x); }

// flag-aware load: isbf!=0 -> buffer is bf16, else fp32
static __device__ __forceinline__ float ldf(const void* p, int i, int isbf){
    return isbf ? b2f(((const bf16*)p)[i]) : ((const float*)p)[i];
}

#define NN    4096
#define FEAT0 500
#define DIN   512
#define NH    256
#define KL1   3072
#define KL2   2304
#define KL3   1728
#define EDGE_CAP 1048576u

typedef __attribute__((ext_vector_type(8)))  short v8s;   // 8 bf16 in 4 VGPRs
typedef __attribute__((ext_vector_type(16))) float v16f;  // 32x32 MFMA acc

// ---------------- per-tensor dtype autodetect ----------------
struct DtIn { const void* p[19]; int n[19]; };
__global__ void k_dtype_all(DtIn a, unsigned* flags){
    int t = threadIdx.x;
    if (t < 19){
        const unsigned short* h = (const unsigned short*)a.p[t];
        int n = a.n[t]; if (n > 256) n = 256;
        int isbf = 1;
        for (int i = 0; i < n; i++){
            unsigned e = ((unsigned)h[i] >> 7) & 0xFFu;
            if (e >= 135u) isbf = 0;
        }
        flags[t] = (unsigned)isbf;
    }
}

// ---------------- init ----------------
__global__ void k_init(float* degA, float* out_acc, unsigned* ecnt, unsigned* maxd2){
    int i = blockIdx.x*256 + threadIdx.x;
    if (i < NN)  degA[i] = 1.0f;          // self-loop
    if (i < 512) out_acc[i] = 0.f;
    if (i == 0){ ecnt[0]=0u; ecnt[1]=0u; ecnt[2]=0u; maxd2[0]=0u; }
}

// ---------------- pos MLP + concat; write fp32 X, bf16 Xb, sq(from bf16) ---
__global__ __launch_bounds__(512) void k_posconcat(const void* __restrict__ feature,
        const void* __restrict__ img, const void* __restrict__ Wpos, const void* __restrict__ bpos,
        const unsigned* __restrict__ dflag, float* __restrict__ X, ushort* __restrict__ Xb,
        float* __restrict__ sq){
    int f_feat = (int)dflag[0], f_img = (int)dflag[1], f_wp = (int)dflag[2], f_bp = (int)dflag[3];
    int row = blockIdx.x, t = threadIdx.x;
    float v;
    if (t < FEAT0) v = ldf(feature, row*FEAT0 + t, f_feat);
    else {
        int c = t - FEAT0;
        float acc = ldf(bpos, c, f_bp);
        #pragma unroll
        for (int d = 0; d < 6; d++) acc += ldf(img, row*6+d, f_img) * ldf(Wpos, d*12+c, f_wp);
        v = fmaxf(acc, 0.f);
    }
    X[row*DIN + t] = v;
    bf16 vb = __float2bfloat16(v);
    Xb[row*DIN + t] = __bfloat16_as_ushort(vb);
    float vr = b2f(vb);                 // sq from rounded values: d2 is exact
    __shared__ float red[512];          // squared distance of the bf16 vectors
    red[t] = vr*vr;
    __syncthreads();
    for (int s = 256; s > 0; s >>= 1){ if (t < s) red[t] += red[t+s]; __syncthreads(); }
    if (t == 0) sq[row] = red[0];
}

// ---------------- Gram via MFMA, 64x64 tile, LDS-staged, low-pressure ------
// Round 7 lesson: 128-tile (4 accs + 8 prefetch float4) exceeded what the
// allocator would keep in regs -> per-chunk scratch spill (46 MB WRITE_SIZE,
// ~900cyc serialized fills, 82 us). This version: 1 acc + 4 prefetch float4
// per thread (~60 live regs), 2080 blocks for latency hiding.
// LDS swizzle: 16B granule g of row r at g^(r&7) -> 2-phase (free) reads.
template<int PASS>
__global__ __launch_bounds__(256) void k_gram(const ushort* __restrict__ Xb,
        const float* __restrict__ sq, unsigned* __restrict__ maxd2,
        unsigned* __restrict__ ecnt, unsigned* __restrict__ edges, float* __restrict__ deg){
    int rb = blockIdx.x, cb = blockIdx.y;
    if (cb > rb) return;                  // lower triangle only (uniform exit)
    __shared__ __align__(16) ushort As[64*64];
    __shared__ __align__(16) ushort Bs[64*64];
    int tid = threadIdx.x;
    int lane = tid & 63, wv = tid >> 6;
    int wwr = wv >> 1, wwc = wv & 1;      // wave quadrant (32x32) of the 64x64 tile
    int l31 = lane & 31, hi = lane >> 5;
    int r7 = l31 & 7;

    // staging: 512 granule-slots per panel (64 rows x 8 x 16B); thread t does
    // slots t and t+256 for each panel. Consecutive t -> contiguous 16B.
    int row0 = tid >> 3,        g0 = tid & 7;
    int row1 = (tid+256) >> 3,  g1 = tid & 7;   // (t+256)&7 == t&7
    const size_t baseA = (size_t)rb*64*DIN;
    const size_t baseB = (size_t)cb*64*DIN;
    int d0 = row0*64 + ((g0^(row0&7))<<3);
    int d1 = row1*64 + ((g1^(row1&7))<<3);

    float4 a0p = *(const float4*)(Xb + baseA + (size_t)row0*DIN + g0*8);
    float4 a1p = *(const float4*)(Xb + baseA + (size_t)row1*DIN + g1*8);
    float4 b0p = *(const float4*)(Xb + baseB + (size_t)row0*DIN + g0*8);
    float4 b1p = *(const float4*)(Xb + baseB + (size_t)row1*DIN + g1*8);

    v16f acc = {};
    int ra0 = (wwr*32 + l31)*64;          // LDS ushort index of A frag row
    int rb0 = (wwc*32 + l31)*64;
    int fr7a = (wwr*32 + l31) & 7;        // same as r7 but explicit
    int fr7b = (wwc*32 + l31) & 7;

    for (int c = 0; c < 8; c++){
        __syncthreads();                  // prior chunk's reads complete
        *(float4*)&As[d0] = a0p;  *(float4*)&As[d1] = a1p;
        *(float4*)&Bs[d0] = b0p;  *(float4*)&Bs[d1] = b1p;
        __syncthreads();
        if (c < 7){
            int k0 = (c+1)*64;
            a0p = *(const float4*)(Xb + baseA + (size_t)row0*DIN + k0 + g0*8);
            a1p = *(const float4*)(Xb + baseA + (size_t)row1*DIN + k0 + g1*8);
            b0p = *(const float4*)(Xb + baseB + (size_t)row0*DIN + k0 + g0*8);
            b1p = *(const float4*)(Xb + baseB + (size_t)row1*DIN + k0 + g1*8);
        }
        #pragma unroll
        for (int ks = 0; ks < 4; ks++){
            int gq = ks*2 + hi;
            v8s a = *(const v8s*)&As[ra0 + ((gq^fr7a)<<3)];
            v8s b = *(const v8s*)&Bs[rb0 + ((gq^fr7b)<<3)];
            acc = __builtin_amdgcn_mfma_f32_32x32x16_bf16(a, b, acc, 0, 0, 0);
        }
    }

    int rbase = rb*64 + wwr*32 + 4*hi;
    int col   = cb*64 + wwc*32 + l31;
    float sqc = sq[col];
    if (PASS == 1){
        float m = 0.f;
        #pragma unroll
        for (int i = 0; i < 16; i++){
            int r = rbase + (i&3) + 8*(i>>2);
            float d2 = sq[r] + sqc - 2.f*acc[i];
            if (r != col) m = fmaxf(m, d2);
        }
        #pragma unroll
        for (int off = 32; off >= 1; off >>= 1) m = fmaxf(m, __shfl_down(m, off));
        if (lane == 0) atomicMax(maxd2, __float_as_uint(fmaxf(m, 0.f)));
    } else {
        float tthr = 0.5f * __uint_as_float(maxd2[0]);
        #pragma unroll
        for (int i = 0; i < 16; i++){
            int r = rbase + (i&3) + 8*(i>>2);
            float d2 = sq[r] + sqc - 2.f*acc[i];
            if (r > col && d2 < tthr){
                unsigned idx = atomicAdd(ecnt, 1u);
                if (idx < EDGE_CAP){
                    edges[idx] = ((unsigned)r << 16) | (unsigned)col;  // dst<<16|src
                    atomicAdd(&deg[r], 1.0f);
                }
            }
        }
    }
}

// ---------------- X @ W (fp32 x flag-dtype -> fp32), 64x64 tiles ----------------
__global__ __launch_bounds__(256) void k_xw(const float* __restrict__ X, const void* __restrict__ W,
        const unsigned* __restrict__ wflag, float* __restrict__ Y, int M, int K){
    int isbf = (int)wflag[0];
    int rb = blockIdx.x, cb = blockIdx.y;      // grid (M/64, 4)
    __shared__ float As[16][68];
    __shared__ float Bs[16][68];
    int tid = threadIdx.x;
    int tx = tid & 15, ty = tid >> 4;
    int lr = tid >> 2, lk = (tid & 3) << 2;    // A-tile load mapping
    int bn = tid & 63, bk4 = (tid >> 6) << 2;  // B-tile load mapping
    const float* Ap = X + (size_t)(rb*64 + lr)*K + lk;
    float acc[4][4] = {};
    for (int k0 = 0; k0 < K; k0 += 16){
        float4 fa = *(const float4*)(Ap + k0);
        int wb = cb*64 + bn;
        float w0 = ldf(W, (k0+bk4+0)*NH + wb, isbf);
        float w1 = ldf(W, (k0+bk4+1)*NH + wb, isbf);
        float w2 = ldf(W, (k0+bk4+2)*NH + wb, isbf);
        float w3 = ldf(W, (k0+bk4+3)*NH + wb, isbf);
        __syncthreads();
        As[lk+0][lr]=fa.x; As[lk+1][lr]=fa.y; As[lk+2][lr]=fa.z; As[lk+3][lr]=fa.w;
        Bs[bk4+0][bn]=w0; Bs[bk4+1][bn]=w1; Bs[bk4+2][bn]=w2; Bs[bk4+3][bn]=w3;
        __syncthreads();
        #pragma unroll
        for (int kk = 0; kk < 16; kk++){
            const float4 av = *(const float4*)(&As[kk][ty<<2]);
            const float4 bv = *(const float4*)(&Bs[kk][tx<<2]);
            const float ar[4] = {av.x,av.y,av.z,av.w};
            const float br[4] = {bv.x,bv.y,bv.z,bv.w};
            #pragma unroll
            for (int i = 0; i < 4; i++)
                #pragma unroll
                for (int j = 0; j < 4; j++)
                    acc[i][j] = fmaf(ar[i], br[j], acc[i][j]);
        }
    }
    int r0 = rb*64 + (ty<<2), c0 = cb*64 + (tx<<2);
    #pragma unroll
    for (int i = 0; i < 4; i++)
        #pragma unroll
        for (int j = 0; j < 4; j++)
            Y[(size_t)(r0+i)*NH + (c0+j)] = acc[i][j];
}

// xw' = dis*xw (in place) ; agg = xw' (self term of A+I)
__global__ void k_scaleself(float* __restrict__ xw, float* __restrict__ agg,
        const float* __restrict__ deg, int N){
    int idx = blockIdx.x*256 + threadIdx.x;
    if (idx >= N*NH) return;
    int row = idx >> 8;
    float dis = 1.0f / sqrtf(deg[row]);
    float v = xw[idx] * dis;
    xw[idx] = v; agg[idx] = v;
}

// agg[dst] += xw'[src] for each edge
__global__ __launch_bounds__(256) void k_edgeagg(const unsigned* __restrict__ edges,
        const unsigned* __restrict__ ecnt, int slot,
        const float* __restrict__ xwp, float* __restrict__ agg){
    unsigned E = ecnt[slot]; if (E > EDGE_CAP) E = EDGE_CAP;
    int t = threadIdx.x;
    for (unsigned e = blockIdx.x; e < E; e += gridDim.x){
        unsigned ed = edges[e];
        int dst = ed >> 16, src = ed & 0xFFFFu;
        atomicAdd(&agg[dst*NH + t], xwp[src*NH + t]);
    }
}

// x = relu(dis*agg + b)
__global__ void k_gcnfin(const float* __restrict__ agg, const float* __restrict__ deg,
        const void* __restrict__ b, const unsigned* __restrict__ bflag,
        float* __restrict__ xout, int N){
    int isbf = (int)bflag[0];
    int idx = blockIdx.x*256 + threadIdx.x;
    if (idx >= N*NH) return;
    int row = idx >> 8, c = idx & 255;
    float dis = 1.0f / sqrtf(deg[row]);
    xout[idx] = fmaxf(fmaf(dis, agg[idx], ldf(b, c, isbf)), 0.f);
}

// per-row: s1 = x.Wn ; z = x.Wr + bs
__global__ __launch_bounds__(256) void k_scorer(const float* __restrict__ X,
        const void* __restrict__ Wn, const void* __restrict__ Wr, const void* __restrict__ bs,
        const unsigned* __restrict__ fWn, const unsigned* __restrict__ fWr,
        const unsigned* __restrict__ fbs, float* __restrict__ s1, float* __restrict__ z){
    int isWn = (int)fWn[0], isWr = (int)fWr[0], isbs = (int)fbs[0];
    int row = blockIdx.x, t = threadIdx.x;
    float xv = X[row*NH + t];
    float a = xv * ldf(Wn, t, isWn);
    float b = xv * ldf(Wr, t, isWr);
    for (int off = 32; off >= 1; off >>= 1){ a += __shfl_down(a, off); b += __shfl_down(b, off); }
    __shared__ float ra[4], rb[4];
    int w = t >> 6;
    if ((t & 63) == 0){ ra[w] = a; rb[w] = b; }
    __syncthreads();
    if (t == 0){
        s1[row] = ra[0]+ra[1]+ra[2]+ra[3];
        z[row]  = rb[0]+rb[1]+rb[2]+rb[3] + ldf(bs, 0, isbs);
    }
}

// z[dst] += s1[src] per edge
__global__ void k_scoredge(const unsigned* __restrict__ edges, const unsigned* __restrict__ ecnt,
        int slot, const float* __restrict__ s1, float* __restrict__ z){
    unsigned E = ecnt[slot]; if (E > EDGE_CAP) E = EDGE_CAP;
    int gid = blockIdx.x*blockDim.x + threadIdx.x;
    int stride = gridDim.x*blockDim.x;
    for (unsigned e = gid; e < E; e += stride)
        atomicAdd(&z[edges[e] >> 16], s1[edges[e] & 0xFFFFu]);
}

// single-block bitonic sort of (tanh(z), idx), descending score, ties -> lower idx
__global__ __launch_bounds__(1024) void k_sort(const float* __restrict__ z, int N,
        int* __restrict__ perm, float* __restrict__ svals){
    __shared__ float sv[4096];
    __shared__ int   si[4096];
    int t = threadIdx.x;
    for (int i = t; i < 4096; i += 1024){
        sv[i] = (i < N) ? tanhf(z[i]) : -INFINITY;
        si[i] = i;
    }
    __syncthreads();
    for (int k = 2; k <= 4096; k <<= 1){
        for (int j = k >> 1; j > 0; j >>= 1){
            for (int i = t; i < 4096; i += 1024){
                int ixj = i ^ j;
                if (ixj > i){
                    bool dirAsc = ((i & k) == 0);
                    float v1 = sv[i], v2 = sv[ixj];
                    int  i1 = si[i], i2 = si[ixj];
                    bool after = (v1 < v2) || (v1 == v2 && i1 > i2);
                    if (after == dirAsc){ sv[i]=v2; sv[ixj]=v1; si[i]=i2; si[ixj]=i1; }
                }
            }
            __syncthreads();
        }
    }
    for (int i = t; i < 4096; i += 1024){ perm[i] = si[i]; svals[i] = sv[i]; }
}

__global__ void k_rankdeg(int* __restrict__ rank, int Ncur, float* __restrict__ degN, int Nnext){
    int i = blockIdx.x*256 + threadIdx.x;
    if (i < Ncur)  rank[i] = -1;
    if (i < Nnext) degN[i] = 1.0f;
}

// pooled x = x[perm[r]] * vals[r] ; also scatter rank
__global__ void k_poolx(const float* __restrict__ X, const int* __restrict__ perm,
        const float* __restrict__ svals, float* __restrict__ Y, int* __restrict__ rank,
        int k, int doRank){
    int idx = blockIdx.x*256 + threadIdx.x;
    int r = idx >> 8, c = idx & 255;
    if (r >= k) return;
    int p = perm[r];
    Y[idx] = X[p*NH + c] * svals[r];
    if (doRank && c == 0) rank[p] = r;
}

// filter surviving edges, renumber, accumulate next-layer degree
__global__ void k_efilter(const unsigned* __restrict__ ein, const unsigned* __restrict__ ecnt, int slotIn,
        unsigned* __restrict__ eout, unsigned* __restrict__ cntOut,
        const int* __restrict__ rank, float* __restrict__ degN){
    unsigned E = ecnt[slotIn]; if (E > EDGE_CAP) E = EDGE_CAP;
    int gid = blockIdx.x*blockDim.x + threadIdx.x;
    int stride = gridDim.x*blockDim.x;
    for (unsigned e = gid; e < E; e += stride){
        unsigned ed = ein[e];
        int nd = rank[ed >> 16], ns = rank[ed & 0xFFFFu];
        if (nd >= 0 && ns >= 0){
            unsigned idx = atomicAdd(cntOut, 1u);
            if (idx < EDGE_CAP){
                eout[idx] = ((unsigned)nd << 16) | (unsigned)ns;
                atomicAdd(&degN[nd], 1.0f);
            }
        }
    }
}

// readout: partial col-max/col-sum over 64 row-stripes, then combine into out_acc
__global__ __launch_bounds__(256) void k_rpart(const float* __restrict__ X, int k,
        float* __restrict__ pmax, float* __restrict__ psum){
    int b = blockIdx.x, t = threadIdx.x;
    float m = -INFINITY, s = 0.f;
    for (int r = b; r < k; r += 64){
        float v = X[r*NH + t];
        m = fmaxf(m, v); s += v;
    }
    pmax[b*NH + t] = m; psum[b*NH + t] = s;
}
__global__ __launch_bounds__(256) void k_rfin(const float* __restrict__ pmax,
        const float* __restrict__ psum, float* __restrict__ out_acc, float invk){
    int t = threadIdx.x;
    float m = -INFINITY, s = 0.f;
    for (int b = 0; b < 64; b++){ m = fmaxf(m, pmax[b*NH+t]); s += psum[b*NH+t]; }
    out_acc[t]      += m;
    out_acc[NH + t] += s * invk;
}

__global__ void k_writeout(const float* __restrict__ out_acc, float* __restrict__ out){
    int t = blockIdx.x*256 + threadIdx.x;
    if (t < 512) out[t] = out_acc[t];
}

// =======================================================================
extern "C" void kernel_launch(void* const* d_in, const int* in_sizes, int n_in,
                              void* d_out, int out_size, void* d_ws, size_t ws_size,
                              hipStream_t stream)
{
    const void* feature = d_in[0];
    const void* img     = d_in[1];
    const void* Wpos    = d_in[2];
    const void* bpos    = d_in[3];
    const void* W1 = d_in[4];  const void* b1 = d_in[5];
    const void* W2 = d_in[6];  const void* b2 = d_in[7];
    const void* W3 = d_in[8];  const void* b3 = d_in[9];
    const void* Wr1 = d_in[10]; const void* Wn1 = d_in[11]; const void* bs1 = d_in[12];
    const void* Wr2 = d_in[13]; const void* Wn2 = d_in[14]; const void* bs2 = d_in[15];
    const void* Wr3 = d_in[16]; const void* Wn3 = d_in[17]; const void* bs3 = d_in[18];

    char* w = (char*)d_ws;
    auto alloc = [&](size_t bytes)->char*{ char* p = w; w += (bytes + 255) & ~(size_t)255; return p; };
    float*    X      = (float*)   alloc((size_t)NN*DIN*4);  // 8 MB: feat, then pooled x
    ushort*   Xb     = (ushort*)  alloc((size_t)NN*DIN*2);  // 4 MB: bf16 X for MFMA gram
    float*    Xn     = (float*)   alloc((size_t)NN*NH*4);   // 4 MB
    float*    XW     = (float*)   alloc((size_t)NN*NH*4);   // 4 MB
    float*    AGG    = (float*)   alloc((size_t)NN*NH*4);   // 4 MB
    unsigned* E0     = (unsigned*)alloc((size_t)EDGE_CAP*4);// 4 MB
    unsigned* E1     = (unsigned*)alloc((size_t)EDGE_CAP*4);// 4 MB
    float*    sq     = (float*)   alloc(NN*4);
    float*    degA   = (float*)   alloc(NN*4);
    float*    degB   = (float*)   alloc(NN*4);
    float*    s1     = (float*)   alloc(NN*4);
    float*    z      = (float*)   alloc(NN*4);
    int*      perm   = (int*)     alloc(NN*4);
    float*    svals  = (float*)   alloc(NN*4);
    int*      rank   = (int*)     alloc(NN*4);
    unsigned* ecnt   = (unsigned*)alloc(256);
    unsigned* maxd2  = (unsigned*)alloc(256);
    unsigned* dflag  = (unsigned*)alloc(256);
    float*    outacc = (float*)   alloc(512*4);
    float*    pmax   = (float*)   alloc(64*NH*4);
    float*    psum   = (float*)   alloc(64*NH*4);
    (void)ws_size;

    DtIn da;
    for (int i = 0; i < 19; i++){ da.p[i] = d_in[i]; da.n[i] = in_sizes[i]; }
    k_dtype_all<<<1, 64, 0, stream>>>(da, dflag);
    k_init<<<16, 256, 0, stream>>>(degA, outacc, ecnt, maxd2);
    k_posconcat<<<NN, 512, 0, stream>>>(feature, img, Wpos, bpos, dflag, X, Xb, sq);
    dim3 gg(64, 64);
    k_gram<1><<<gg, 256, 0, stream>>>(Xb, sq, maxd2, ecnt, E0, degA);
    k_gram<2><<<gg, 256, 0, stream>>>(Xb, sq, maxd2, ecnt, E0, degA);

    // ---------------- layer 1 (N=4096 -> k=3072) ----------------
    k_xw<<<dim3(64,4), 256, 0, stream>>>(X, W1, dflag+4, XW, NN, DIN);
    k_scaleself<<<NN, 256, 0, stream>>>(XW, AGG, degA, NN);
    k_edgeagg<<<512, 256, 0, stream>>>(E0, ecnt, 0, XW, AGG);
    k_gcnfin<<<NN, 256, 0, stream>>>(AGG, degA, b1, dflag+5, Xn, NN);
    k_scorer<<<NN, 256, 0, stream>>>(Xn, Wn1, Wr1, bs1, dflag+11, dflag+10, dflag+12, s1, z);
    k_scoredge<<<256, 256, 0, stream>>>(E0, ecnt, 0, s1, z);
    k_sort<<<1, 1024, 0, stream>>>(z, NN, perm, svals);
    k_rankdeg<<<16, 256, 0, stream>>>(rank, NN, degB, KL1);
    k_poolx<<<KL1, 256, 0, stream>>>(Xn, perm, svals, X, rank, KL1, 1);
    k_rpart<<<64, 256, 0, stream>>>(X, KL1, pmax, psum);
    k_rfin<<<1, 256, 0, stream>>>(pmax, psum, outacc, 1.0f/KL1);
    k_efilter<<<256, 256, 0, stream>>>(E0, ecnt, 0, E1, ecnt+1, rank, degB);

    // ---------------- layer 2 (N=3072 -> k=2304) ----------------
    k_xw<<<dim3(48,4), 256, 0, stream>>>(X, W2, dflag+6, XW, KL1, NH);
    k_scaleself<<<KL1, 256, 0, stream>>>(XW, AGG, degB, KL1);
    k_edgeagg<<<512, 256, 0, stream>>>(E1, ecnt, 1, XW, AGG);
    k_gcnfin<<<KL1, 256, 0, stream>>>(AGG, degB, b2, dflag+7, Xn, KL1);
    k_scorer<<<KL1, 256, 0, stream>>>(Xn, Wn2, Wr2, bs2, dflag+14, dflag+13, dflag+15, s1, z);
    k_scoredge<<<256, 256, 0, stream>>>(E1, ecnt, 1, s1, z);
    k_sort<<<1, 1024, 0, stream>>>(z, KL1, perm, svals);
    k_rankdeg<<<16, 256, 0, stream>>>(rank, KL1, degA, KL2);
    k_poolx<<<KL2, 256, 0, stream>>>(Xn, perm, svals, X, rank, KL2, 1);
    k_rpart<<<64, 256, 0, stream>>>(X, KL2, pmax, psum);
    k_rfin<<<1, 256, 0, stream>>>(pmax, psum, outacc, 1.0f/KL2);
    k_efilter<<<256, 256, 0, stream>>>(E1, ecnt, 1, E0, ecnt+2, rank, degA);

    // ---------------- layer 3 (N=2304 -> k=1728) ----------------
    k_xw<<<dim3(36,4), 256, 0, stream>>>(X, W3, dflag+8, XW, KL2, NH);
    k_scaleself<<<KL2, 256, 0, stream>>>(XW, AGG, degA, KL2);
    k_edgeagg<<<512, 256, 0, stream>>>(E0, ecnt, 2, XW, AGG);
    k_gcnfin<<<KL2, 256, 0, stream>>>(AGG, degA, b3, dflag+9, Xn, KL2);
    k_scorer<<<KL2, 256, 0, stream>>>(Xn, Wn3, Wr3, bs3, dflag+17, dflag+16, dflag+18, s1, z);
    k_scoredge<<<256, 256, 0, stream>>>(E0, ecnt, 2, s1, z);
    k_sort<<<1, 1024, 0, stream>>>(z, KL2, perm, svals);
    k_poolx<<<KL3, 256, 0, stream>>>(Xn, perm, svals, X, rank, KL3, 0);
    k_rpart<<<64, 256, 0, stream>>>(X, KL3, pmax, psum);
    k_rfin<<<1, 256, 0, stream>>>(pmax, psum, outacc, 1.0f/KL3);

    k_writeout<<<2, 256, 0, stream>>>(outacc, (float*)d_out);
}

// Round 9
// 460.198 us; speedup vs baseline: 1.4037x; 1.3323x over previous
//
#include <hip/hip_runtime.h>
#include <hip/hip_bf16.h>
#include <math.h>

typedef __hip_bfloat16 bf16;
typedef unsigned short ushort;
typedef unsigned int uint;
static __device__ __forceinline__ float b2f(bf16 x){ return __bfloat162float(x); }

// flag-aware load: isbf!=0 -> buffer is bf16, else fp32
static __device__ __forceinline__ float ldf(const void* p, int i, int isbf){
    return isbf ? b2f(((const bf16*)p)[i]) : ((const float*)p)[i];
}
// order-preserving float<->uint coding (works for negatives; no NaNs in data)
static __device__ __forceinline__ uint fcode(float v){
    uint u = __float_as_uint(v);
    return (u & 0x80000000u) ? ~u : (u | 0x80000000u);
}
static __device__ __forceinline__ float fdecode(uint c){
    uint u = (c & 0x80000000u) ? (c & 0x7FFFFFFFu) : ~c;
    return __uint_as_float(u);
}

#define NN    4096
#define FEAT0 500
#define DIN   512
#define NH    256
#define KL1   3072
#define KL2   2304
#define KL3   1728
#define EDGE_CAP 786432u

typedef __attribute__((ext_vector_type(8)))  short v8s;   // 8 bf16 in 4 VGPRs
typedef __attribute__((ext_vector_type(16))) float v16f;  // 32x32 MFMA acc

// ---------------- init + per-tensor dtype autodetect -----------------------
struct DtIn { const void* p[19]; int n[19]; };
__global__ void k_initall(DtIn a, unsigned* flags, float* degA, uint* maxU, float* sums,
        unsigned* ecnt, unsigned* maxd2){
    int i = blockIdx.x*256 + threadIdx.x;
    if (i < NN)  degA[i] = 1.0f;              // self-loop
    if (i < 768){ maxU[i] = 0x007FFFFFu; sums[i] = 0.f; }   // fcode(-inf)
    if (i == 0){ ecnt[0]=0u; ecnt[1]=0u; ecnt[2]=0u; maxd2[0]=0u; }
    if (blockIdx.x == 0 && threadIdx.x < 19){
        int t = threadIdx.x;
        const unsigned short* h = (const unsigned short*)a.p[t];
        int n = a.n[t]; if (n > 256) n = 256;
        int isbf = 1;
        for (int j = 0; j < n; j++){
            unsigned e = ((unsigned)h[j] >> 7) & 0xFFu;
            if (e >= 135u) isbf = 0;          // |v|>=64 impossible for true bf16 data here
        }
        flags[t] = (unsigned)isbf;
    }
}

// ---------------- pos MLP + concat; write bf16 Xb, sq(from bf16) -----------
__global__ __launch_bounds__(512) void k_posconcat(const void* __restrict__ feature,
        const void* __restrict__ img, const void* __restrict__ Wpos, const void* __restrict__ bpos,
        const unsigned* __restrict__ dflag, ushort* __restrict__ Xb, float* __restrict__ sq){
    int f_feat = (int)dflag[0], f_img = (int)dflag[1], f_wp = (int)dflag[2], f_bp = (int)dflag[3];
    int row = blockIdx.x, t = threadIdx.x;
    float v;
    if (t < FEAT0) v = ldf(feature, row*FEAT0 + t, f_feat);
    else {
        int c = t - FEAT0;
        float acc = ldf(bpos, c, f_bp);
        #pragma unroll
        for (int d = 0; d < 6; d++) acc += ldf(img, row*6+d, f_img) * ldf(Wpos, d*12+c, f_wp);
        v = fmaxf(acc, 0.f);
    }
    bf16 vb = __float2bfloat16(v);
    Xb[row*DIN + t] = __bfloat16_as_ushort(vb);
    float vr = b2f(vb);                 // sq of rounded vector -> d2 exact for bf16 X
    __shared__ float red[512];
    red[t] = vr*vr;
    __syncthreads();
    for (int s = 256; s > 0; s >>= 1){ if (t < s) red[t] += red[t+s]; __syncthreads(); }
    if (t == 0) sq[row] = red[0];
}

// ---------------- convert W1/W2/W3 to bf16 (once) --------------------------
__global__ void k_wconv(const void* __restrict__ W1, const void* __restrict__ W2,
        const void* __restrict__ W3, const unsigned* __restrict__ dflag, ushort* __restrict__ Wb){
    int i0 = blockIdx.x*1024 + threadIdx.x*4;
    #pragma unroll
    for (int j = 0; j < 4; j++){
        int idx = i0 + j;
        float v;
        if (idx < 131072)       v = ldf(W1, idx,          (int)dflag[4]);
        else if (idx < 196608)  v = ldf(W2, idx - 131072, (int)dflag[6]);
        else                    v = ldf(W3, idx - 196608, (int)dflag[8]);
        Wb[idx] = __bfloat16_as_ushort(__float2bfloat16(v));
    }
}

// ---------------- Gram via MFMA, 64x64 tile, LDS-staged (round-8 proven) ---
template<int PASS>
__global__ __launch_bounds__(256) void k_gram(const ushort* __restrict__ Xb,
        const float* __restrict__ sq, unsigned* __restrict__ maxd2,
        unsigned* __restrict__ ecnt, unsigned* __restrict__ edges, float* __restrict__ deg){
    int rb = blockIdx.x, cb = blockIdx.y;
    if (cb > rb) return;                  // lower triangle only (uniform exit)
    __shared__ __align__(16) ushort As[64*64];
    __shared__ __align__(16) ushort Bs[64*64];
    int tid = threadIdx.x;
    int lane = tid & 63, wv = tid >> 6;
    int wwr = wv >> 1, wwc = wv & 1;
    int l31 = lane & 31, hi = lane >> 5;

    int row0 = tid >> 3,       g0 = tid & 7;
    int row1 = (tid+256) >> 3, g1 = tid & 7;
    const size_t baseA = (size_t)rb*64*DIN;
    const size_t baseB = (size_t)cb*64*DIN;
    int d0 = row0*64 + ((g0^(row0&7))<<3);
    int d1 = row1*64 + ((g1^(row1&7))<<3);

    float4 a0p = *(const float4*)(Xb + baseA + (size_t)row0*DIN + g0*8);
    float4 a1p = *(const float4*)(Xb + baseA + (size_t)row1*DIN + g1*8);
    float4 b0p = *(const float4*)(Xb + baseB + (size_t)row0*DIN + g0*8);
    float4 b1p = *(const float4*)(Xb + baseB + (size_t)row1*DIN + g1*8);

    v16f acc = {};
    int ra0 = (wwr*32 + l31)*64;
    int rb0 = (wwc*32 + l31)*64;
    int fr7a = (wwr*32 + l31) & 7;
    int fr7b = (wwc*32 + l31) & 7;

    for (int c = 0; c < 8; c++){
        __syncthreads();
        *(float4*)&As[d0] = a0p;  *(float4*)&As[d1] = a1p;
        *(float4*)&Bs[d0] = b0p;  *(float4*)&Bs[d1] = b1p;
        __syncthreads();
        if (c < 7){
            int k0 = (c+1)*64;
            a0p = *(const float4*)(Xb + baseA + (size_t)row0*DIN + k0 + g0*8);
            a1p = *(const float4*)(Xb + baseA + (size_t)row1*DIN + k0 + g1*8);
            b0p = *(const float4*)(Xb + baseB + (size_t)row0*DIN + k0 + g0*8);
            b1p = *(const float4*)(Xb + baseB + (size_t)row1*DIN + k0 + g1*8);
        }
        #pragma unroll
        for (int ks = 0; ks < 4; ks++){
            int gq = ks*2 + hi;
            v8s a = *(const v8s*)&As[ra0 + ((gq^fr7a)<<3)];
            v8s b = *(const v8s*)&Bs[rb0 + ((gq^fr7b)<<3)];
            acc = __builtin_amdgcn_mfma_f32_32x32x16_bf16(a, b, acc, 0, 0, 0);
        }
    }

    int rbase = rb*64 + wwr*32 + 4*hi;
    int col   = cb*64 + wwc*32 + l31;
    float sqc = sq[col];
    if (PASS == 1){
        float m = 0.f;
        #pragma unroll
        for (int i = 0; i < 16; i++){
            int r = rbase + (i&3) + 8*(i>>2);
            float d2 = sq[r] + sqc - 2.f*acc[i];
            if (r != col) m = fmaxf(m, d2);
        }
        #pragma unroll
        for (int off = 32; off >= 1; off >>= 1) m = fmaxf(m, __shfl_down(m, off));
        if (lane == 0) atomicMax(maxd2, __float_as_uint(fmaxf(m, 0.f)));
    } else {
        float tthr = 0.5f * __uint_as_float(maxd2[0]);
        #pragma unroll
        for (int i = 0; i < 16; i++){
            int r = rbase + (i&3) + 8*(i>>2);
            float d2 = sq[r] + sqc - 2.f*acc[i];
            if (r > col && d2 < tthr){
                unsigned idx = atomicAdd(ecnt, 1u);
                if (idx < EDGE_CAP){
                    edges[idx] = ((unsigned)r << 16) | (unsigned)col;  // dst<<16|src
                    atomicAdd(&deg[r], 1.0f);
                }
            }
        }
    }
}

// ---------------- X @ W via MFMA (bf16), fused dis-scale + self-agg --------
// A: M x K bf16 row-major. Wb: K x 256 bf16 row-major. Out: XW' = dis*(A@W),
// AGG = XW' (self term). 64x64 tile, BK=64, same swizzle as k_gram.
__global__ __launch_bounds__(256) void k_xw(const ushort* __restrict__ Ab,
        const ushort* __restrict__ Wb, const float* __restrict__ deg,
        float* __restrict__ XW, float* __restrict__ AGG, int M, int K){
    int rb = blockIdx.x, cb = blockIdx.y;     // (M/64, 4)
    __shared__ __align__(16) ushort As[64*64];
    __shared__ __align__(16) ushort Bs[64*64]; // Bs[n*64+kk] = W[k0+kk][cb*64+n]
    int tid = threadIdx.x, lane = tid & 63, wv = tid >> 6;
    int wwr = wv >> 1, wwc = wv & 1;
    int l31 = lane & 31, hi = lane >> 5;

    int arow0 = tid >> 3, ag = tid & 7;
    int arow1 = arow0 + 32;
    int da0 = arow0*64 + ((ag^(arow0&7))<<3);
    int da1 = arow1*64 + ((ag^(arow1&7))<<3);
    const size_t baseA = (size_t)rb*64*K;
    int kr = tid >> 2, ng = tid & 3;          // B: thread covers W[kr][ng*16..+15]

    float4 a0p = *(const float4*)(Ab + baseA + (size_t)arow0*K + ag*8);
    float4 a1p = *(const float4*)(Ab + baseA + (size_t)arow1*K + ag*8);
    float4 b0p = *(const float4*)(Wb + (size_t)kr*NH + cb*64 + ng*16);
    float4 b1p = *(const float4*)(Wb + (size_t)kr*NH + cb*64 + ng*16 + 8);

    v16f acc = {};
    int ra0 = (wwr*32 + l31)*64;
    int rb0 = (wwc*32 + l31)*64;
    int fr7a = (wwr*32 + l31) & 7;
    int fr7b = (wwc*32 + l31) & 7;
    int kg = kr >> 3, k7 = kr & 7;

    int NC = K >> 6;
    for (int c = 0; c < NC; c++){
        __syncthreads();
        *(float4*)&As[da0] = a0p; *(float4*)&As[da1] = a1p;
        const ushort* bw0 = (const ushort*)&b0p;
        const ushort* bw1 = (const ushort*)&b1p;
        #pragma unroll
        for (int j = 0; j < 8; j++){
            int nn = ng*16 + j;
            Bs[nn*64 + ((kg^(nn&7))<<3) + k7] = bw0[j];
        }
        #pragma unroll
        for (int j = 0; j < 8; j++){
            int nn = ng*16 + 8 + j;
            Bs[nn*64 + ((kg^(nn&7))<<3) + k7] = bw1[j];
        }
        __syncthreads();
        if (c + 1 < NC){
            int k0 = (c+1)*64;
            a0p = *(const float4*)(Ab + baseA + (size_t)arow0*K + k0 + ag*8);
            a1p = *(const float4*)(Ab + baseA + (size_t)arow1*K + k0 + ag*8);
            b0p = *(const float4*)(Wb + (size_t)(k0+kr)*NH + cb*64 + ng*16);
            b1p = *(const float4*)(Wb + (size_t)(k0+kr)*NH + cb*64 + ng*16 + 8);
        }
        #pragma unroll
        for (int ks = 0; ks < 4; ks++){
            int gq = ks*2 + hi;
            v8s a = *(const v8s*)&As[ra0 + ((gq^fr7a)<<3)];
            v8s b = *(const v8s*)&Bs[rb0 + ((gq^fr7b)<<3)];
            acc = __builtin_amdgcn_mfma_f32_32x32x16_bf16(a, b, acc, 0, 0, 0);
        }
    }
    int n  = cb*64 + wwc*32 + l31;
    int mb = rb*64 + wwr*32 + 4*hi;
    #pragma unroll
    for (int i = 0; i < 16; i++){
        int m = mb + (i&3) + 8*(i>>2);
        float dis = 1.0f / sqrtf(deg[m]);
        float v = acc[i] * dis;
        size_t o = (size_t)m*NH + n;
        XW[o] = v; AGG[o] = v;
    }
}

// agg[dst] += xw'[src] for each edge
__global__ __launch_bounds__(256) void k_edgeagg(const unsigned* __restrict__ edges,
        const unsigned* __restrict__ ecnt, int slot,
        const float* __restrict__ xwp, float* __restrict__ agg){
    unsigned E = ecnt[slot]; if (E > EDGE_CAP) E = EDGE_CAP;
    int t = threadIdx.x;
    for (unsigned e = blockIdx.x; e < E; e += gridDim.x){
        unsigned ed = edges[e];
        int dst = ed >> 16, src = ed & 0xFFFFu;
        atomicAdd(&agg[dst*NH + t], xwp[src*NH + t]);
    }
}

// x = relu(dis*agg + b); fused scorer: s1 = x.Wn ; z = x.Wr + bs
__global__ __launch_bounds__(256) void k_gcnscore(const float* __restrict__ AGG,
        const float* __restrict__ deg, const void* __restrict__ b,
        const void* __restrict__ Wn, const void* __restrict__ Wr, const void* __restrict__ bs,
        const unsigned* __restrict__ fb, const unsigned* __restrict__ fWn,
        const unsigned* __restrict__ fWr, const unsigned* __restrict__ fbs,
        float* __restrict__ Xn, float* __restrict__ s1, float* __restrict__ z){
    int row = blockIdx.x, t = threadIdx.x;
    float dis = 1.0f / sqrtf(deg[row]);
    float xn = fmaxf(fmaf(dis, AGG[row*NH + t], ldf(b, t, (int)fb[0])), 0.f);
    Xn[row*NH + t] = xn;
    float a  = xn * ldf(Wn, t, (int)fWn[0]);
    float bb = xn * ldf(Wr, t, (int)fWr[0]);
    for (int off = 32; off >= 1; off >>= 1){ a += __shfl_down(a, off); bb += __shfl_down(bb, off); }
    __shared__ float ra[4], rbv[4];
    int w = t >> 6;
    if ((t & 63) == 0){ ra[w] = a; rbv[w] = bb; }
    __syncthreads();
    if (t == 0){
        s1[row] = ra[0]+ra[1]+ra[2]+ra[3];
        z[row]  = rbv[0]+rbv[1]+rbv[2]+rbv[3] + ldf(bs, 0, (int)fbs[0]);
    }
}

// z[dst] += s1[src] per edge
__global__ void k_scoredge(const unsigned* __restrict__ edges, const unsigned* __restrict__ ecnt,
        int slot, const float* __restrict__ s1, float* __restrict__ z){
    unsigned E = ecnt[slot]; if (E > EDGE_CAP) E = EDGE_CAP;
    int gid = blockIdx.x*blockDim.x + threadIdx.x;
    int stride = gridDim.x*blockDim.x;
    for (unsigned e = gid; e < E; e += stride)
        atomicAdd(&z[edges[e] >> 16], s1[edges[e] & 0xFFFFu]);
}

// ---------------- top-k set via single-block radix select ------------------
// Readout is order-invariant and renumbering arbitrary -> only the SET and
// vals matter; tanh is monotone so select on raw z. Also inits rank/degN.
__global__ __launch_bounds__(1024) void k_select(const float* __restrict__ z, int N, int k,
        int* __restrict__ perm, float* __restrict__ svals, int* __restrict__ rank,
        float* __restrict__ degN, int Nnext){
    __shared__ uint keys[4096];
    __shared__ uint hist[256];
    __shared__ uint sh[4];    // 0:prefix 1:rem 2:selCnt 3:eqCnt
    int t = threadIdx.x;
    for (int i = t; i < N; i += 1024){ keys[i] = fcode(z[i]); rank[i] = -1; }
    for (int i = t; i < Nnext; i += 1024) degN[i] = 1.0f;
    if (t == 0){ sh[0] = 0u; sh[1] = (uint)k; sh[2] = 0u; sh[3] = 0u; }
    __syncthreads();
    uint prefmask = 0u;
    for (int pass = 0; pass < 4; pass++){
        int shift = 24 - 8*pass;
        if (t < 256) hist[t] = 0u;
        __syncthreads();
        uint prefix = sh[0];
        for (int i = t; i < N; i += 1024){
            uint ky = keys[i];
            if ((ky & prefmask) == prefix) atomicAdd(&hist[(ky >> shift) & 255u], 1u);
        }
        __syncthreads();
        if (t == 0){
            uint rem = sh[1], cum = 0u;
            for (int bidx = 255; bidx >= 0; bidx--){
                uint c = hist[bidx];
                if (cum + c >= rem){ sh[0] = prefix | ((uint)bidx << shift); sh[1] = rem - cum; break; }
                cum += c;
            }
        }
        prefmask |= (0xFFu << shift);
        __syncthreads();
    }
    uint T = sh[0], rem = sh[1];
    for (int i = t; i < N; i += 1024){
        uint ky = keys[i];
        bool sel = (ky > T);
        if (!sel && ky == T){ uint e = atomicAdd(&sh[3], 1u); sel = (e < rem); }
        if (sel){
            uint r = atomicAdd(&sh[2], 1u);
            perm[r] = i;
            svals[r] = tanhf(z[i]);
            rank[i] = (int)r;
        }
    }
}

// pooled: Pf (fp32, for readout) and Pb (bf16, for next x@W)
__global__ void k_poolx(const float* __restrict__ Xn, const int* __restrict__ perm,
        const float* __restrict__ svals, float* __restrict__ Pf, ushort* __restrict__ Pb, int k){
    int idx = blockIdx.x*256 + threadIdx.x;
    int r = idx >> 8, c = idx & 255;
    if (r >= k) return;
    float v = Xn[perm[r]*NH + c] * svals[r];
    Pf[idx] = v;
    Pb[idx] = __bfloat16_as_ushort(__float2bfloat16(v));
}

// filter surviving edges, renumber, accumulate next-layer degree
__global__ void k_efilter(const unsigned* __restrict__ ein, const unsigned* __restrict__ ecnt, int slotIn,
        unsigned* __restrict__ eout, unsigned* __restrict__ cntOut,
        const int* __restrict__ rank, float* __restrict__ degN){
    unsigned E = ecnt[slotIn]; if (E > EDGE_CAP) E = EDGE_CAP;
    int gid = blockIdx.x*blockDim.x + threadIdx.x;
    int stride = gridDim.x*blockDim.x;
    for (unsigned e = gid; e < E; e += stride){
        unsigned ed = ein[e];
        int nd = rank[ed >> 16], ns = rank[ed & 0xFFFFu];
        if (nd >= 0 && ns >= 0){
            unsigned idx = atomicAdd(cntOut, 1u);
            if (idx < EDGE_CAP){
                eout[idx] = ((unsigned)nd << 16) | (unsigned)ns;
                atomicAdd(&degN[nd], 1.0f);
            }
        }
    }
}

// fused readout: col-max (uint-coded atomicMax) + col-sum (atomicAdd) per layer
__global__ __launch_bounds__(256) void k_readout(const float* __restrict__ P, int k,
        uint* __restrict__ maxU, float* __restrict__ sums, int layer){
    int b = blockIdx.x, t = threadIdx.x;
    float m = -INFINITY, s = 0.f;
    for (int r = b; r < k; r += 64){ float v = P[r*NH + t]; m = fmaxf(m, v); s += v; }
    atomicMax(&maxU[layer*NH + t], fcode(m));
    atomicAdd(&sums[layer*NH + t], s);
}

__global__ void k_writeout(const uint* __restrict__ maxU, const float* __restrict__ sums,
        float* __restrict__ out, float i1, float i2, float i3){
    int t = threadIdx.x;
    if (blockIdx.x == 0)
        out[t] = fdecode(maxU[t]) + fdecode(maxU[NH + t]) + fdecode(maxU[2*NH + t]);
    else
        out[NH + t] = sums[t]*i1 + sums[NH + t]*i2 + sums[2*NH + t]*i3;
}

// =======================================================================
extern "C" void kernel_launch(void* const* d_in, const int* in_sizes, int n_in,
                              void* d_out, int out_size, void* d_ws, size_t ws_size,
                              hipStream_t stream)
{
    const void* feature = d_in[0];
    const void* img     = d_in[1];
    const void* Wpos    = d_in[2];
    const void* bpos    = d_in[3];
    const void* W1 = d_in[4];  const void* b1 = d_in[5];
    const void* W2 = d_in[6];  const void* b2 = d_in[7];
    const void* W3 = d_in[8];  const void* b3 = d_in[9];
    const void* Wr1 = d_in[10]; const void* Wn1 = d_in[11]; const void* bs1 = d_in[12];
    const void* Wr2 = d_in[13]; const void* Wn2 = d_in[14]; const void* bs2 = d_in[15];
    const void* Wr3 = d_in[16]; const void* Wn3 = d_in[17]; const void* bs3 = d_in[18];

    char* w = (char*)d_ws;
    auto alloc = [&](size_t bytes)->char*{ char* p = w; w += (bytes + 255) & ~(size_t)255; return p; };
    ushort*   Xb    = (ushort*)  alloc((size_t)NN*DIN*2);   // 4 MB
    float*    Xn    = (float*)   alloc((size_t)NN*NH*4);    // 4 MB
    float*    XW    = (float*)   alloc((size_t)NN*NH*4);    // 4 MB
    float*    AGG   = (float*)   alloc((size_t)NN*NH*4);    // 4 MB
    float*    Pf    = (float*)   alloc((size_t)KL1*NH*4);   // 3 MB pooled fp32
    ushort*   Pb    = (ushort*)  alloc((size_t)KL1*NH*2);   // 1.5 MB pooled bf16
    ushort*   Wb    = (ushort*)  alloc((size_t)262144*2);   // 0.5 MB W1|W2|W3 bf16
    unsigned* E0    = (unsigned*)alloc((size_t)EDGE_CAP*4); // 3 MB
    unsigned* E1    = (unsigned*)alloc((size_t)EDGE_CAP*4); // 3 MB
    float*    sq    = (float*)   alloc(NN*4);
    float*    degA  = (float*)   alloc(NN*4);
    float*    degB  = (float*)   alloc(NN*4);
    float*    s1    = (float*)   alloc(NN*4);
    float*    z     = (float*)   alloc(NN*4);
    int*      perm  = (int*)     alloc(NN*4);
    float*    svals = (float*)   alloc(NN*4);
    int*      rank  = (int*)     alloc(NN*4);
    unsigned* ecnt  = (unsigned*)alloc(256);
    unsigned* maxd2 = (unsigned*)alloc(256);
    unsigned* dflag = (unsigned*)alloc(256);
    uint*     maxU  = (uint*)    alloc(768*4);
    float*    sums  = (float*)   alloc(768*4);
    (void)ws_size;

    DtIn da;
    for (int i = 0; i < 19; i++){ da.p[i] = d_in[i]; da.n[i] = in_sizes[i]; }
    k_initall<<<16, 256, 0, stream>>>(da, dflag, degA, maxU, sums, ecnt, maxd2);
    k_posconcat<<<NN, 512, 0, stream>>>(feature, img, Wpos, bpos, dflag, Xb, sq);
    k_wconv<<<256, 256, 0, stream>>>(W1, W2, W3, dflag, Wb);
    dim3 gg(64, 64);
    k_gram<1><<<gg, 256, 0, stream>>>(Xb, sq, maxd2, ecnt, E0, degA);
    k_gram<2><<<gg, 256, 0, stream>>>(Xb, sq, maxd2, ecnt, E0, degA);

    // ---------------- layer 1 (N=4096 -> k=3072) ----------------
    k_xw<<<dim3(64,4), 256, 0, stream>>>(Xb, Wb, degA, XW, AGG, NN, DIN);
    k_edgeagg<<<512, 256, 0, stream>>>(E0, ecnt, 0, XW, AGG);
    k_gcnscore<<<NN, 256, 0, stream>>>(AGG, degA, b1, Wn1, Wr1, bs1,
            dflag+5, dflag+11, dflag+10, dflag+12, Xn, s1, z);
    k_scoredge<<<256, 256, 0, stream>>>(E0, ecnt, 0, s1, z);
    k_select<<<1, 1024, 0, stream>>>(z, NN, KL1, perm, svals, rank, degB, KL1);
    k_poolx<<<KL1, 256, 0, stream>>>(Xn, perm, svals, Pf, Pb, KL1);
    k_readout<<<64, 256, 0, stream>>>(Pf, KL1, maxU, sums, 0);
    k_efilter<<<256, 256, 0, stream>>>(E0, ecnt, 0, E1, ecnt+1, rank, degB);

    // ---------------- layer 2 (N=3072 -> k=2304) ----------------
    k_xw<<<dim3(48,4), 256, 0, stream>>>(Pb, Wb + 131072, degB, XW, AGG, KL1, NH);
    k_edgeagg<<<512, 256, 0, stream>>>(E1, ecnt, 1, XW, AGG);
    k_gcnscore<<<KL1, 256, 0, stream>>>(AGG, degB, b2, Wn2, Wr2, bs2,
            dflag+7, dflag+14, dflag+13, dflag+15, Xn, s1, z);
    k_scoredge<<<256, 256, 0, stream>>>(E1, ecnt, 1, s1, z);
    k_select<<<1, 1024, 0, stream>>>(z, KL1, KL2, perm, svals, rank, degA, KL2);
    k_poolx<<<KL2, 256, 0, stream>>>(Xn, perm, svals, Pf, Pb, KL2);
    k_readout<<<64, 256, 0, stream>>>(Pf, KL2, maxU, sums, 1);
    k_efilter<<<256, 256, 0, stream>>>(E1, ecnt, 1, E0, ecnt+2, rank, degA);

    // ---------------- layer 3 (N=2304 -> k=1728) ----------------
    k_xw<<<dim3(36,4), 256, 0, stream>>>(Pb, Wb + 196608, degA, XW, AGG, KL2, NH);
    k_edgeagg<<<512, 256, 0, stream>>>(E0, ecnt, 2, XW, AGG);
    k_gcnscore<<<KL2, 256, 0, stream>>>(AGG, degA, b3, Wn3, Wr3, bs3,
            dflag+9, dflag+17, dflag+16, dflag+18, Xn, s1, z);
    k_scoredge<<<256, 256, 0, stream>>>(E0, ecnt, 2, s1, z);
    k_select<<<1, 1024, 0, stream>>>(z, KL2, KL3, perm, svals, rank, degB, 0);
    k_poolx<<<KL3, 256, 0, stream>>>(Xn, perm, svals, Pf, Pb, KL3);
    k_readout<<<64, 256, 0, stream>>>(Pf, KL3, maxU, sums, 2);

    k_writeout<<<2, 256, 0, stream>>>(maxU, sums, (float*)d_out,
            1.0f/KL1, 1.0f/KL2, 1.0f/KL3);
}